// Round 9
// baseline (2171.218 us; speedup 1.0000x reference)
//
#include <hip/hip_runtime.h>
#include <math.h>

typedef __bf16 bf16x8 __attribute__((ext_vector_type(8)));
typedef float  f32x4  __attribute__((ext_vector_type(4)));
typedef unsigned long long u64;

#define AST 520    // activation LDS stride (bf16 elems), 16 rows
#define UST 2056   // u LDS stride

__device__ __forceinline__ float gelu_f(float x) {
  const float k0 = 0.7978845608028654f;
  const float k1 = 0.044715f;
  float x3 = x * x * x;
  return 0.5f * x * (1.0f + tanhf(k0 * (x + k1 * x3)));
}

// ---------------- prep: pool + weight transposes + Wv pack + y conv + beff ----------------
__global__ __launch_bounds__(256) void prep_kernel(
    const float* __restrict__ xe,
    const float* __restrict__ Wpi, const float* __restrict__ Wpa,
    const float* __restrict__ Wc,  const float* __restrict__ w1f,
    const float* __restrict__ w2f, const float* __restrict__ wo,
    const float* __restrict__ wqkv, const float* __restrict__ y,
    const float* __restrict__ bqkv, const float* __restrict__ bo,
    __bf16* __restrict__ xp_b,
    __bf16* __restrict__ WpiT, __bf16* __restrict__ WpaT,
    __bf16* __restrict__ WcabT, __bf16* __restrict__ WccT,
    __bf16* __restrict__ w1T,  __bf16* __restrict__ w2T,
    __bf16* __restrict__ woT,  __bf16* __restrict__ Wv_b,
    __bf16* __restrict__ y_b,  float* __restrict__ beff)
{
  int bid = blockIdx.x;
  int tid = threadIdx.x;
  if (bid < 512) {               // mean pool (128,512,1024) -> (128,1024) bf16
    int b = bid >> 2;
    int c = (bid & 3) * 256 + tid;
    const float* p = xe + (size_t)b * 512 * 1024 + c;
    float s = 0.f;
#pragma unroll 16
    for (int i = 0; i < 512; ++i) s += p[(size_t)i * 1024];
    xp_b[b * 1024 + c] = (__bf16)(s * (1.f / 512.f));
  } else if (bid < 6528) {       // transposes fp32 -> bf16 (N x K layout)
    int t = bid - 512;
    const float* src; __bf16* dst; int R, C;
    if      (t < 512)  {            src = Wpi;            dst = WpiT;          R = 1024; C = 512;  }
    else if (t < 640)  { t -= 512;  src = Wpa;            dst = WpaT;          R = 256;  C = 512;  }
    else if (t < 1152) { t -= 640;  src = Wc;             dst = WcabT;         R = 1024; C = 512;  }
    else if (t < 1408) { t -= 1152; src = Wc + 1024*512;  dst = WccT;          R = 512;  C = 512;  }
    else if (t < 2432) { t -= 1408; src = w1f;            dst = w1T;           R = 512;  C = 2048; }
    else if (t < 3456) { t -= 2432; src = w1f + 512*2048; dst = w1T + 1048576; R = 512;  C = 2048; }
    else if (t < 4480) { t -= 3456; src = w2f;            dst = w2T;           R = 2048; C = 512;  }
    else if (t < 5504) { t -= 4480; src = w2f + 2048*512; dst = w2T + 1048576; R = 2048; C = 512;  }
    else if (t < 5760) { t -= 5504; src = wo;             dst = woT;           R = 512;  C = 512;  }
    else               { t -= 5760; src = wo + 512*512;   dst = woT + 262144;  R = 512;  C = 512;  }
    int nbc = C / 32;
    int r0 = (t / nbc) * 32;
    int c0 = (t % nbc) * 32;
    __shared__ float tt[32][33];
    int tx = tid & 31, ty = tid >> 5;
#pragma unroll
    for (int i = 0; i < 32; i += 8)
      tt[ty + i][tx] = src[(size_t)(r0 + ty + i) * C + c0 + tx];
    __syncthreads();
#pragma unroll
    for (int i = 0; i < 32; i += 8)
      dst[(size_t)(c0 + ty + i) * R + r0 + tx] = (__bf16)tt[tx][ty + i];
  } else if (bid < 6784) {       // Wv pack
    int e0 = ((bid - 6528) * 256 + tid) * 8;
    int l = e0 >> 18, rem = e0 & 262143;
    int m = rem >> 9, k = rem & 511;
    const float* s = wqkv + (size_t)l * 786432 + (size_t)m * 1536 + 1024 + k;
#pragma unroll
    for (int j = 0; j < 8; ++j) Wv_b[e0 + j] = (__bf16)s[j];
  } else if (bid < 6800) {       // y -> bf16
    int e0 = ((bid - 6784) * 256 + tid) * 8;
#pragma unroll
    for (int j = 0; j < 8; ++j) y_b[e0 + j] = (__bf16)y[e0 + j];
  } else {                       // beff[l] = bv @ wo + bo
    int b2 = bid - 6800;
    int l = b2 >> 1;
    int n = (b2 & 1) * 256 + tid;
    const float* bv = bqkv + l * 1536 + 1024;
    const float* w  = wo + (size_t)l * 262144;
    float s = bo[l * 512 + n];
#pragma unroll 8
    for (int k = 0; k < 512; ++k) s += bv[k] * w[(size_t)k * 512 + n];
    beff[l * 512 + n] = s;
  }
}

// ---------------- LDS-tile GEMM (aux only) ----------------
template<int NT, bool BIAS>
__device__ __forceinline__ void gemm32(
    const __bf16* A, const __bf16* Bt, int bm0, int bn0,
    const float* bias, __bf16* outb, int ldo,
    __bf16* AL, __bf16* BL)
{
  const int tid = threadIdx.x;
  constexpr int K = NT * 64;
  const int row = tid >> 3;
  const int kcol = (tid & 7) * 8;

  const __bf16* Ab0 = A + (size_t)(bm0 + row) * K + kcol;
  const __bf16* Bb0 = Bt + (size_t)(bn0 + row) * K + kcol;

  u64 ra0[4], ra1[4], rb0[4], rb1[4];
  auto issue = [&](int t, int s) {
    const __bf16* ap = Ab0 + t * 64;
    const __bf16* bp = Bb0 + t * 64;
    ra0[s] = *(const u64*)ap; ra1[s] = *(const u64*)(ap + 4);
    rb0[s] = *(const u64*)bp; rb1[s] = *(const u64*)(bp + 4);
  };
#pragma unroll
  for (int s = 0; s < 4; ++s) issue(s, s);

  f32x4 acc = {0.f, 0.f, 0.f, 0.f};
  const int wave = tid >> 6, lane = tid & 63;
  const int wr = (wave >> 1) * 16, wc = (wave & 1) * 16;
  const int lr = lane & 15, lk8 = (lane >> 4) * 8;

  for (int ttc = 0; ttc < NT / 4; ++ttc) {
#pragma unroll
    for (int ti = 0; ti < 4; ++ti) {
      const int t = ttc * 4 + ti;
      __bf16* al = AL + (ti & 1) * 2304 + row * 72 + kcol;
      __bf16* bl = BL + (ti & 1) * 2304 + row * 72 + kcol;
      *(u64*)al = ra0[ti]; *(u64*)(al + 4) = ra1[ti];
      *(u64*)bl = rb0[ti]; *(u64*)(bl + 4) = rb1[ti];
      __syncthreads();
      if (t + 4 < NT) issue(t + 4, ti);
      const __bf16* Ar = AL + (ti & 1) * 2304 + (wr + lr) * 72;
      const __bf16* Br = BL + (ti & 1) * 2304 + (wc + lr) * 72;
      bf16x8 a0 = *(const bf16x8*)(Ar + lk8);
      bf16x8 b0v = *(const bf16x8*)(Br + lk8);
      acc = __builtin_amdgcn_mfma_f32_16x16x32_bf16(a0, b0v, acc, 0, 0, 0);
      bf16x8 a1 = *(const bf16x8*)(Ar + 32 + lk8);
      bf16x8 b1v = *(const bf16x8*)(Br + 32 + lk8);
      acc = __builtin_amdgcn_mfma_f32_16x16x32_bf16(a1, b1v, acc, 0, 0, 0);
      __syncthreads();
    }
  }

  const int er = bm0 + wr + (lane >> 4) * 4;
  const int ec = bn0 + wc + lr;
#pragma unroll
  for (int e = 0; e < 4; ++e) {
    float v = acc[e];
    if (BIAS) v += bias[ec];
    outb[(size_t)(er + e) * ldo + ec] = (__bf16)v;
  }
}

// ---------------- aux: Weff GEMMs + projections ----------------
__global__ __launch_bounds__(256) void aux_kernel(
    const __bf16* __restrict__ woT, const __bf16* __restrict__ Wv_b,
    const __bf16* __restrict__ xp_b, const __bf16* __restrict__ y_b,
    const __bf16* __restrict__ WpiT, const __bf16* __restrict__ WpaT,
    const float* __restrict__ bpi, const float* __restrict__ bpa,
    __bf16* __restrict__ WeffT, __bf16* __restrict__ xy_b)
{
  __shared__ __bf16 AL[2 * 32 * 72];
  __shared__ __bf16 BL[2 * 32 * 72];
  int bid = blockIdx.x;
  if (bid < 512) {        // WeffT[l][n][j] = sum_m woT[l][n][m] * Wv_b[l][j][m]
    int l = bid >> 8, t = bid & 255;
    gemm32<8, false>(woT + l * 262144, Wv_b + l * 262144,
        (t >> 4) * 32, (t & 15) * 32, nullptr, WeffT + l * 262144, 512, AL, BL);
  } else if (bid < 576) { // xy[:, :512] = xp @ Wpi + bpi
    int t = bid - 512;
    gemm32<16, true>(xp_b, WpiT, (t >> 4) * 32, (t & 15) * 32,
        bpi, xy_b, 1024, AL, BL);
  } else {                // xy[:, 512:] = y @ Wpa + bpa
    int t = bid - 576;
    gemm32<4, true>(y_b, WpaT, (t >> 4) * 32, (t & 15) * 32,
        bpa, xy_b + 512, 1024, AL, BL);
  }
}

// ---------------- in-place LayerNorm over a 16x512 LDS tile (512 threads) ----------------
__device__ __forceinline__ void ln_inplace(__bf16* A, const float* g, const float* bb) {
  const int tid = threadIdx.x;
  const int row = tid >> 5;
  const int c0 = (tid & 31) * 16;
  __bf16* p = A + row * AST + c0;
  bf16x8 v0 = *(const bf16x8*)p;
  bf16x8 v1 = *(const bf16x8*)(p + 8);
  float s = 0.f, s2 = 0.f;
#pragma unroll
  for (int j = 0; j < 8; ++j) {
    float f0 = (float)v0[j], f1 = (float)v1[j];
    s += f0 + f1; s2 += f0 * f0 + f1 * f1;
  }
#pragma unroll
  for (int m = 1; m <= 16; m <<= 1) { s += __shfl_xor(s, m); s2 += __shfl_xor(s2, m); }
  const float mu = s * (1.f / 512.f);
  const float rs = rsqrtf(s2 * (1.f / 512.f) - mu * mu + 1e-5f);
  const f32x4 g0 = *(const f32x4*)(g + c0);
  const f32x4 g1 = *(const f32x4*)(g + c0 + 4);
  const f32x4 g2 = *(const f32x4*)(g + c0 + 8);
  const f32x4 g3 = *(const f32x4*)(g + c0 + 12);
  const f32x4 b0 = *(const f32x4*)(bb + c0);
  const f32x4 b1 = *(const f32x4*)(bb + c0 + 4);
  const f32x4 b2 = *(const f32x4*)(bb + c0 + 8);
  const f32x4 b3 = *(const f32x4*)(bb + c0 + 12);
#pragma unroll
  for (int j = 0; j < 4; ++j) {
    v0[j]     = (__bf16)(((float)v0[j]     - mu) * rs * g0[j] + b0[j]);
    v0[j + 4] = (__bf16)(((float)v0[j + 4] - mu) * rs * g1[j] + b1[j]);
    v1[j]     = (__bf16)(((float)v1[j]     - mu) * rs * g2[j] + b2[j]);
    v1[j + 4] = (__bf16)(((float)v1[j + 4] - mu) * rs * g3[j] + b3[j]);
  }
  *(bf16x8*)p = v0;
  *(bf16x8*)(p + 8) = v1;
}

// ---------------- per-wave 16x16-tile GEMM: A (LDS or global) x Bt^T (global) ----------------
// acc[nt] += A[rc][k] * Bt[n0+nt*16+rc][k]
template<int KT, int NTILE>
__device__ __forceinline__ void mm16(
    const __bf16* __restrict__ Ab, int astride,
    const __bf16* __restrict__ Bt, int n0, f32x4* acc)
{
  constexpr int K = KT * 32;
  const int lane = threadIdx.x & 63;
  const int rc = lane & 15;
  const int k8 = (lane >> 4) * 8;
  const __bf16* ap = Ab + rc * astride + k8;
  const __bf16* bp = Bt + (size_t)(n0 + rc) * K + k8;
#pragma unroll 4
  for (int t = 0; t < KT; ++t) {
    bf16x8 a = *(const bf16x8*)(ap + t * 32);
#pragma unroll
    for (int nt = 0; nt < NTILE; ++nt) {
      bf16x8 b = *(const bf16x8*)(bp + (size_t)nt * (16 * K) + t * 32);
      acc[nt] = __builtin_amdgcn_mfma_f32_16x16x32_bf16(a, b, acc[nt], 0, 0, 0);
    }
  }
}

// ---------------- mega: 8 independent WGs, one per 16-row group; zero grid sync ----------------
__global__ __launch_bounds__(512, 1) void mega_kernel(
    const __bf16* __restrict__ xy_b, const __bf16* __restrict__ WcabT,
    const __bf16* __restrict__ WccT, const __bf16* __restrict__ WeffT,
    const __bf16* __restrict__ w1T, const __bf16* __restrict__ w2T,
    const float* __restrict__ bc, const float* __restrict__ beff,
    const float* __restrict__ ln1g, const float* __restrict__ ln1b,
    const float* __restrict__ ln2g, const float* __restrict__ ln2b,
    const float* __restrict__ b1f, const float* __restrict__ b2f,
    float* __restrict__ out)
{
  __shared__ __bf16 ACT0[16 * AST];
  __shared__ __bf16 ACT1[16 * AST];
  __shared__ __bf16 ZB[16 * AST];
  __shared__ __bf16 UB[16 * UST];

  const int g = blockIdx.x;            // rows g*16 .. g*16+15
  const int tid = threadIdx.x;
  const int wv = tid >> 6;             // 0..7
  const int lane = tid & 63;
  const int rc = lane & 15;
  const int erow = (lane >> 4) * 4;    // epilogue row base (+e)
  const int cn = wv * 64;              // this wave's 64-col slice
  const int am0 = g * 16;

  f32x4 base_p[4], resC[4], x_p[4], z_p[4];
#pragma unroll
  for (int nt = 0; nt < 4; ++nt) z_p[nt] = f32x4{0.f, 0.f, 0.f, 0.f};

  // BASE: c0 = xy @ Wcab + bc   (K=1024, A global from aux)
  {
    f32x4 acc[4] = {{0,0,0,0},{0,0,0,0},{0,0,0,0},{0,0,0,0}};
    mm16<32, 4>(xy_b + (size_t)am0 * 1024, 1024, WcabT, cn, acc);
#pragma unroll
    for (int nt = 0; nt < 4; ++nt) {
      const int col = cn + nt * 16 + rc;
#pragma unroll
      for (int e = 0; e < 4; ++e) {
        float v = acc[nt][e] + bc[col];
        base_p[nt][e] = v;
        ACT0[(erow + e) * AST + col] = (__bf16)v;
      }
    }
  }
  __syncthreads();

  for (int r = 0; r < 6; ++r) {
    if (r == 0) {
#pragma unroll
      for (int nt = 0; nt < 4; ++nt) resC[nt] = base_p[nt];
    } else {
      // S1: c = base + z @ Wcc
      f32x4 acc[4] = {{0,0,0,0},{0,0,0,0},{0,0,0,0},{0,0,0,0}};
      mm16<16, 4>(ZB, AST, WccT, cn, acc);
#pragma unroll
      for (int nt = 0; nt < 4; ++nt) {
        const int col = cn + nt * 16 + rc;
#pragma unroll
        for (int e = 0; e < 4; ++e) {
          float v = base_p[nt][e] + acc[nt][e];
          resC[nt][e] = v;
          ACT0[(erow + e) * AST + col] = (__bf16)v;
        }
      }
      __syncthreads();
    }
#pragma unroll
    for (int l = 0; l < 2; ++l) {
      // S2: x = resid + LN1(ACT0) @ Weff + beff
      ln_inplace(ACT0, ln1g + l * 512, ln1b + l * 512);
      __syncthreads();
      {
        f32x4 acc[4] = {{0,0,0,0},{0,0,0,0},{0,0,0,0},{0,0,0,0}};
        mm16<16, 4>(ACT0, AST, WeffT + l * 262144, cn, acc);
#pragma unroll
        for (int nt = 0; nt < 4; ++nt) {
          const int col = cn + nt * 16 + rc;
#pragma unroll
          for (int e = 0; e < 4; ++e) {
            float res = (l == 0) ? resC[nt][e] : x_p[nt][e];
            float v = acc[nt][e] + beff[l * 512 + col] + res;
            x_p[nt][e] = v;
            ACT1[(erow + e) * AST + col] = (__bf16)v;
          }
        }
      }
      __syncthreads();
      // S3: u = gelu(LN2(ACT1) @ w1 + b1)  (two half-passes of 8 tiles)
      ln_inplace(ACT1, ln2g + l * 512, ln2b + l * 512);
      __syncthreads();
#pragma unroll
      for (int h = 0; h < 2; ++h) {
        f32x4 a8[8] = {{0,0,0,0},{0,0,0,0},{0,0,0,0},{0,0,0,0},
                       {0,0,0,0},{0,0,0,0},{0,0,0,0},{0,0,0,0}};
        const int n0 = wv * 256 + h * 128;
        mm16<16, 8>(ACT1, AST, w1T + l * 1048576, n0, a8);
#pragma unroll
        for (int nt = 0; nt < 8; ++nt) {
          const int col3 = n0 + nt * 16 + rc;
#pragma unroll
          for (int e = 0; e < 4; ++e)
            UB[(erow + e) * UST + col3] = (__bf16)gelu_f(a8[nt][e] + b1f[l * 2048 + col3]);
        }
      }
      __syncthreads();
      // S4: x = x + u @ w2 + b2 ; l==1 accumulates into z (r==5 -> d_out)
      {
        f32x4 acc[4] = {{0,0,0,0},{0,0,0,0},{0,0,0,0},{0,0,0,0}};
        mm16<64, 4>(UB, UST, w2T + l * 1048576, cn, acc);
        if (l == 0) {
#pragma unroll
          for (int nt = 0; nt < 4; ++nt) {
            const int col = cn + nt * 16 + rc;
#pragma unroll
            for (int e = 0; e < 4; ++e) {
              float v = acc[nt][e] + b2f[col] + x_p[nt][e];
              x_p[nt][e] = v;
              ACT0[(erow + e) * AST + col] = (__bf16)v;
            }
          }
          __syncthreads();
        } else {
#pragma unroll
          for (int nt = 0; nt < 4; ++nt) {
            const int col = cn + nt * 16 + rc;
#pragma unroll
            for (int e = 0; e < 4; ++e) {
              float v = acc[nt][e] + b2f[512 + col] + x_p[nt][e];
              z_p[nt][e] += v;
              if (r < 5) ZB[(erow + e) * AST + col] = (__bf16)z_p[nt][e];
              else       out[(size_t)(am0 + erow + e) * 512 + col] = z_p[nt][e];
            }
          }
          if (r < 5) __syncthreads();
        }
      }
    }
  }
}

extern "C" void kernel_launch(void* const* d_in, const int* in_sizes, int n_in,
                              void* d_out, int out_size, void* d_ws, size_t ws_size,
                              hipStream_t stream) {
  const float* x_encoded = (const float*)d_in[0];
  const float* y_current = (const float*)d_in[1];
  const float* Wpi  = (const float*)d_in[2];
  const float* bpi  = (const float*)d_in[3];
  const float* Wpa  = (const float*)d_in[4];
  const float* bpa  = (const float*)d_in[5];
  const float* Wc   = (const float*)d_in[6];
  const float* bc   = (const float*)d_in[7];
  const float* ln1g = (const float*)d_in[8];
  const float* ln1b = (const float*)d_in[9];
  const float* wqkv = (const float*)d_in[10];
  const float* bqkv = (const float*)d_in[11];
  const float* wo   = (const float*)d_in[12];
  const float* bo   = (const float*)d_in[13];
  const float* ln2g = (const float*)d_in[14];
  const float* ln2b = (const float*)d_in[15];
  const float* w1f  = (const float*)d_in[16];
  const float* b1f  = (const float*)d_in[17];
  const float* w2f  = (const float*)d_in[18];
  const float* b2f  = (const float*)d_in[19];
  (void)in_sizes; (void)n_in; (void)out_size; (void)ws_size;

  char* wsb = (char*)d_ws;
  size_t off = 0;
  auto carve = [&](size_t bytes) -> void* {
    void* p = wsb + off;
    off += (bytes + 255) & ~(size_t)255;
    return p;
  };
  __bf16* xp_b    = (__bf16*)carve(131072 * 2);
  __bf16* y_b     = (__bf16*)carve(32768 * 2);
  __bf16* WpiT    = (__bf16*)carve(524288 * 2);
  __bf16* WpaT    = (__bf16*)carve(131072 * 2);
  __bf16* WcabT   = (__bf16*)carve(524288 * 2);
  __bf16* WccT    = (__bf16*)carve(262144 * 2);
  __bf16* w1T     = (__bf16*)carve(2097152 * 2);
  __bf16* w2T     = (__bf16*)carve(2097152 * 2);
  __bf16* woT     = (__bf16*)carve(524288 * 2);
  __bf16* Wv_b    = (__bf16*)carve(524288 * 2);
  __bf16* WeffT   = (__bf16*)carve(524288 * 2);
  float*  beff    = (float*) carve(1024 * 4);
  __bf16* xy_b    = (__bf16*)carve(131072 * 2);

  prep_kernel<<<6804, 256, 0, stream>>>(x_encoded, Wpi, Wpa, Wc, w1f, w2f, wo,
      wqkv, y_current, bqkv, bo, xp_b, WpiT, WpaT, WcabT, WccT, w1T, w2T, woT,
      Wv_b, y_b, beff);
  aux_kernel<<<640, 256, 0, stream>>>(woT, Wv_b, xp_b, y_b, WpiT, WpaT,
      bpi, bpa, WeffT, xy_b);
  mega_kernel<<<8, 512, 0, stream>>>(
      xy_b, WcabT, WccT, WeffT, w1T, w2T, bc, beff,
      ln1g, ln1b, ln2g, ln2b, b1f, b2f,
      (float*)d_out);
}

// Round 10
// 500.541 us; speedup vs baseline: 4.3377x; 4.3377x over previous
//
#include <hip/hip_runtime.h>
#include <math.h>

typedef __bf16 bf16x8 __attribute__((ext_vector_type(8)));
typedef float  f32x4  __attribute__((ext_vector_type(4)));
typedef unsigned long long u64;

#define STR 2056   // LDS A stride (bf16 elems): 2-way bank aliasing only

__device__ __forceinline__ float gelu_f(float x) {
  const float k0 = 0.7978845608028654f;
  const float k1 = 0.044715f;
  float x3 = x * x * x;
  return 0.5f * x * (1.0f + tanhf(k0 * (x + k1 * x3)));
}

// coherent (agent-scope, IF$-backed) accessors: bypass non-coherent per-XCD L2
__device__ __forceinline__ u64 cload8(const void* p) {
  return __hip_atomic_load((u64*)p, __ATOMIC_RELAXED, __HIP_MEMORY_SCOPE_AGENT);
}
__device__ __forceinline__ void cstore_bf16(__bf16* p, __bf16 h) {
  __hip_atomic_store((short*)p, __builtin_bit_cast(short, h),
                     __ATOMIC_RELAXED, __HIP_MEMORY_SCOPE_AGENT);
}

// ---------------- prep: pool + weight transposes + Wv pack + y conv + beff ----------------
__global__ __launch_bounds__(256) void prep_kernel(
    const float* __restrict__ xe,
    const float* __restrict__ Wpi, const float* __restrict__ Wpa,
    const float* __restrict__ Wc,  const float* __restrict__ w1f,
    const float* __restrict__ w2f, const float* __restrict__ wo,
    const float* __restrict__ wqkv, const float* __restrict__ y,
    const float* __restrict__ bqkv, const float* __restrict__ bo,
    __bf16* __restrict__ xp_b,
    __bf16* __restrict__ WpiT, __bf16* __restrict__ WpaT,
    __bf16* __restrict__ WcabT, __bf16* __restrict__ WccT,
    __bf16* __restrict__ w1T,  __bf16* __restrict__ w2T,
    __bf16* __restrict__ woT,  __bf16* __restrict__ Wv_b,
    __bf16* __restrict__ y_b,  float* __restrict__ beff)
{
  int bid = blockIdx.x;
  int tid = threadIdx.x;
  if (bid < 512) {               // mean pool (128,512,1024) -> (128,1024) bf16
    int b = bid >> 2;
    int c = (bid & 3) * 256 + tid;
    const float* p = xe + (size_t)b * 512 * 1024 + c;
    float s = 0.f;
#pragma unroll 16
    for (int i = 0; i < 512; ++i) s += p[(size_t)i * 1024];
    xp_b[b * 1024 + c] = (__bf16)(s * (1.f / 512.f));
  } else if (bid < 6528) {       // transposes fp32 -> bf16 (N x K layout)
    int t = bid - 512;
    const float* src; __bf16* dst; int R, C;
    if      (t < 512)  {            src = Wpi;            dst = WpiT;          R = 1024; C = 512;  }
    else if (t < 640)  { t -= 512;  src = Wpa;            dst = WpaT;          R = 256;  C = 512;  }
    else if (t < 1152) { t -= 640;  src = Wc;             dst = WcabT;         R = 1024; C = 512;  }
    else if (t < 1408) { t -= 1152; src = Wc + 1024*512;  dst = WccT;          R = 512;  C = 512;  }
    else if (t < 2432) { t -= 1408; src = w1f;            dst = w1T;           R = 512;  C = 2048; }
    else if (t < 3456) { t -= 2432; src = w1f + 512*2048; dst = w1T + 1048576; R = 512;  C = 2048; }
    else if (t < 4480) { t -= 3456; src = w2f;            dst = w2T;           R = 2048; C = 512;  }
    else if (t < 5504) { t -= 4480; src = w2f + 2048*512; dst = w2T + 1048576; R = 2048; C = 512;  }
    else if (t < 5760) { t -= 5504; src = wo;             dst = woT;           R = 512;  C = 512;  }
    else               { t -= 5760; src = wo + 512*512;   dst = woT + 262144;  R = 512;  C = 512;  }
    int nbc = C / 32;
    int r0 = (t / nbc) * 32;
    int c0 = (t % nbc) * 32;
    __shared__ float tt[32][33];
    int tx = tid & 31, ty = tid >> 5;
#pragma unroll
    for (int i = 0; i < 32; i += 8)
      tt[ty + i][tx] = src[(size_t)(r0 + ty + i) * C + c0 + tx];
    __syncthreads();
#pragma unroll
    for (int i = 0; i < 32; i += 8)
      dst[(size_t)(c0 + ty + i) * R + r0 + tx] = (__bf16)tt[tx][ty + i];
  } else if (bid < 6784) {       // Wv pack
    int e0 = ((bid - 6528) * 256 + tid) * 8;
    int l = e0 >> 18, rem = e0 & 262143;
    int m = rem >> 9, k = rem & 511;
    const float* s = wqkv + (size_t)l * 786432 + (size_t)m * 1536 + 1024 + k;
#pragma unroll
    for (int j = 0; j < 8; ++j) Wv_b[e0 + j] = (__bf16)s[j];
  } else if (bid < 6800) {       // y -> bf16
    int e0 = ((bid - 6784) * 256 + tid) * 8;
#pragma unroll
    for (int j = 0; j < 8; ++j) y_b[e0 + j] = (__bf16)y[e0 + j];
  } else {                       // beff[l] = bv @ wo + bo
    int b2 = bid - 6800;
    int l = b2 >> 1;
    int n = (b2 & 1) * 256 + tid;
    const float* bv = bqkv + l * 1536 + 1024;
    const float* w  = wo + (size_t)l * 262144;
    float s = bo[l * 512 + n];
#pragma unroll 8
    for (int k = 0; k < 512; ++k) s += bv[k] * w[(size_t)k * 512 + n];
    beff[l * 512 + n] = s;
  }
}

// ---------------- LDS-tile GEMM (aux only) ----------------
template<int NT, bool BIAS>
__device__ __forceinline__ void gemm32(
    const __bf16* A, const __bf16* Bt, int bm0, int bn0,
    const float* bias, __bf16* outb, int ldo,
    __bf16* AL, __bf16* BL)
{
  const int tid = threadIdx.x;
  constexpr int K = NT * 64;
  const int row = tid >> 3;
  const int kcol = (tid & 7) * 8;

  const __bf16* Ab0 = A + (size_t)(bm0 + row) * K + kcol;
  const __bf16* Bb0 = Bt + (size_t)(bn0 + row) * K + kcol;

  u64 ra0[4], ra1[4], rb0[4], rb1[4];
  auto issue = [&](int t, int s) {
    const __bf16* ap = Ab0 + t * 64;
    const __bf16* bp = Bb0 + t * 64;
    ra0[s] = *(const u64*)ap; ra1[s] = *(const u64*)(ap + 4);
    rb0[s] = *(const u64*)bp; rb1[s] = *(const u64*)(bp + 4);
  };
#pragma unroll
  for (int s = 0; s < 4; ++s) issue(s, s);

  f32x4 acc = {0.f, 0.f, 0.f, 0.f};
  const int wave = tid >> 6, lane = tid & 63;
  const int wr = (wave >> 1) * 16, wc = (wave & 1) * 16;
  const int lr = lane & 15, lk8 = (lane >> 4) * 8;

  for (int ttc = 0; ttc < NT / 4; ++ttc) {
#pragma unroll
    for (int ti = 0; ti < 4; ++ti) {
      const int t = ttc * 4 + ti;
      __bf16* al = AL + (ti & 1) * 2304 + row * 72 + kcol;
      __bf16* bl = BL + (ti & 1) * 2304 + row * 72 + kcol;
      *(u64*)al = ra0[ti]; *(u64*)(al + 4) = ra1[ti];
      *(u64*)bl = rb0[ti]; *(u64*)(bl + 4) = rb1[ti];
      __syncthreads();
      if (t + 4 < NT) issue(t + 4, ti);
      const __bf16* Ar = AL + (ti & 1) * 2304 + (wr + lr) * 72;
      const __bf16* Br = BL + (ti & 1) * 2304 + (wc + lr) * 72;
      bf16x8 a0 = *(const bf16x8*)(Ar + lk8);
      bf16x8 b0v = *(const bf16x8*)(Br + lk8);
      acc = __builtin_amdgcn_mfma_f32_16x16x32_bf16(a0, b0v, acc, 0, 0, 0);
      bf16x8 a1 = *(const bf16x8*)(Ar + 32 + lk8);
      bf16x8 b1v = *(const bf16x8*)(Br + 32 + lk8);
      acc = __builtin_amdgcn_mfma_f32_16x16x32_bf16(a1, b1v, acc, 0, 0, 0);
      __syncthreads();
    }
  }

  const int er = bm0 + wr + (lane >> 4) * 4;
  const int ec = bn0 + wc + lr;
#pragma unroll
  for (int e = 0; e < 4; ++e) {
    float v = acc[e];
    if (BIAS) v += bias[ec];
    outb[(size_t)(er + e) * ldo + ec] = (__bf16)v;
  }
}

// ---------------- aux: Weff GEMMs + projections ----------------
__global__ __launch_bounds__(256) void aux_kernel(
    const __bf16* __restrict__ woT, const __bf16* __restrict__ Wv_b,
    const __bf16* __restrict__ xp_b, const __bf16* __restrict__ y_b,
    const __bf16* __restrict__ WpiT, const __bf16* __restrict__ WpaT,
    const float* __restrict__ bpi, const float* __restrict__ bpa,
    __bf16* __restrict__ WeffT, __bf16* __restrict__ xy_b)
{
  __shared__ __bf16 AL[2 * 32 * 72];
  __shared__ __bf16 BL[2 * 32 * 72];
  int bid = blockIdx.x;
  if (bid < 512) {        // WeffT[l][n][j] = sum_m woT[l][n][m] * Wv_b[l][j][m]
    int l = bid >> 8, t = bid & 255;
    gemm32<8, false>(woT + l * 262144, Wv_b + l * 262144,
        (t >> 4) * 32, (t & 15) * 32, nullptr, WeffT + l * 262144, 512, AL, BL);
  } else if (bid < 576) { // xy[:, :512] = xp @ Wpi + bpi
    int t = bid - 512;
    gemm32<16, true>(xp_b, WpiT, (t >> 4) * 32, (t & 15) * 32,
        bpi, xy_b, 1024, AL, BL);
  } else {                // xy[:, 512:] = y @ Wpa + bpa
    int t = bid - 576;
    gemm32<4, true>(y_b, WpaT, (t >> 4) * 32, (t & 15) * 32,
        bpa, xy_b + 512, 1024, AL, BL);
  }
}

// ---------------- 8-WG group barrier: own slot store + all-to-all poll ----------------
__device__ __forceinline__ void gbar(int* slots, int p, int ep) {
  asm volatile("s_waitcnt vmcnt(0)" ::: "memory");
  __syncthreads();
  if (threadIdx.x == 0)
    __hip_atomic_store(slots + p * 32, ep, __ATOMIC_RELAXED, __HIP_MEMORY_SCOPE_AGENT);
  if (threadIdx.x < 8) {
    while (__hip_atomic_load(slots + threadIdx.x * 32, __ATOMIC_RELAXED,
                             __HIP_MEMORY_SCOPE_AGENT) < ep)
      __builtin_amdgcn_s_sleep(1);
  }
  __syncthreads();
}

// ---------------- stage 16 x K activation rows into LDS (flat copy, 512 threads) ----------
template<int LGK, bool COH>
__device__ __forceinline__ void stageA(__bf16* A, const __bf16* __restrict__ src) {
  constexpr int K = 1 << LGK;
#pragma unroll
  for (int i = threadIdx.x; i < (16 << LGK) / 4; i += 512) {
    const int i4 = i * 4;
    u64 q;
    if (COH) q = cload8(src + i4);
    else     q = *(const u64*)(src + i4);
    *(u64*)&A[(i4 >> LGK) * STR + (i4 & (K - 1))] = q;
  }
}

// ---------------- in-place LayerNorm over 16 x 512 LDS tile (512 threads) ----------------
__device__ __forceinline__ void ln_lds(__bf16* A, const float* __restrict__ g,
                                       const float* __restrict__ bb) {
  const int tid = threadIdx.x;
  const int row = tid >> 5;
  const int c0 = (tid & 31) * 16;
  __bf16* p = A + row * STR + c0;
  bf16x8 v0 = *(const bf16x8*)p;
  bf16x8 v1 = *(const bf16x8*)(p + 8);
  float s = 0.f, s2 = 0.f;
#pragma unroll
  for (int j = 0; j < 8; ++j) {
    float f0 = (float)v0[j], f1 = (float)v1[j];
    s += f0 + f1; s2 += f0 * f0 + f1 * f1;
  }
#pragma unroll
  for (int m = 1; m <= 16; m <<= 1) { s += __shfl_xor(s, m); s2 += __shfl_xor(s2, m); }
  const float mu = s * (1.f / 512.f);
  const float rs = rsqrtf(s2 * (1.f / 512.f) - mu * mu + 1e-5f);
  const f32x4 g0 = *(const f32x4*)(g + c0);
  const f32x4 g1 = *(const f32x4*)(g + c0 + 4);
  const f32x4 g2 = *(const f32x4*)(g + c0 + 8);
  const f32x4 g3 = *(const f32x4*)(g + c0 + 12);
  const f32x4 b0 = *(const f32x4*)(bb + c0);
  const f32x4 b1 = *(const f32x4*)(bb + c0 + 4);
  const f32x4 b2 = *(const f32x4*)(bb + c0 + 8);
  const f32x4 b3 = *(const f32x4*)(bb + c0 + 12);
#pragma unroll
  for (int j = 0; j < 4; ++j) {
    v0[j]     = (__bf16)(((float)v0[j]     - mu) * rs * g0[j] + b0[j]);
    v0[j + 4] = (__bf16)(((float)v0[j + 4] - mu) * rs * g1[j] + b1[j]);
    v1[j]     = (__bf16)(((float)v1[j]     - mu) * rs * g2[j] + b2[j]);
    v1[j + 4] = (__bf16)(((float)v1[j + 4] - mu) * rs * g3[j] + b3[j]);
  }
  *(bf16x8*)p = v0;
  *(bf16x8*)(p + 8) = v1;
}

// ---------------- K-split GEMM: 8 waves = 4 tiles x 2 K-halves; partials to P ----------------
// A in LDS (stride STR); Bt global [N][KT*64] row-major. Wave w: tile nt=w&3, half kh=w>>2.
template<int KT>
__device__ __forceinline__ void gemm_ks(const __bf16* A, const __bf16* __restrict__ Bt,
                                        int ncol0, float* P) {
  const int tid = threadIdx.x;
  const int w = tid >> 6, lane = tid & 63;
  const int rc = lane & 15, k8 = (lane >> 4) * 8;
  const int nt = w & 3, kh = w >> 2;
  const __bf16* ap = A + rc * STR + kh * (KT * 32) + k8;
  const __bf16* bp = Bt + (size_t)(ncol0 + nt * 16 + rc) * (KT * 64) + kh * (KT * 32) + k8;
  f32x4 acc = {0.f, 0.f, 0.f, 0.f};
#pragma unroll
  for (int t = 0; t < KT; ++t)
    acc = __builtin_amdgcn_mfma_f32_16x16x32_bf16(
        *(const bf16x8*)(ap + t * 32), *(const bf16x8*)(bp + t * 32), acc, 0, 0, 0);
  const int row0 = (lane >> 4) * 4;
#pragma unroll
  for (int e = 0; e < 4; ++e)
    P[kh * 1088 + (row0 + e) * 68 + nt * 16 + rc] = acc[e];
}

// reduce partials for wave w<4 (tile w)
__device__ __forceinline__ f32x4 red_ks(const float* P) {
  const int tid = threadIdx.x;
  const int w = tid >> 6, lane = tid & 63;
  const int rc = lane & 15, row0 = (lane >> 4) * 4;
  f32x4 v;
#pragma unroll
  for (int e = 0; e < 4; ++e)
    v[e] = P[(row0 + e) * 68 + w * 16 + rc] + P[1088 + (row0 + e) * 68 + w * 16 + rc];
  return v;
}

// ---------------- mega: 64 WGs = 8 row-groups x 8 col-slices (col-slice == XCD) ----------------
__global__ __launch_bounds__(512, 1) void mega_kernel(
    const __bf16* __restrict__ xy_b, const __bf16* __restrict__ WcabT,
    const __bf16* __restrict__ WccT, const __bf16* __restrict__ WeffT,
    const __bf16* __restrict__ w1T, const __bf16* __restrict__ w2T,
    const float* __restrict__ bc, const float* __restrict__ beff,
    const float* __restrict__ ln1g, const float* __restrict__ ln1b,
    const float* __restrict__ ln2g, const float* __restrict__ ln2b,
    const float* __restrict__ b1f, const float* __restrict__ b2f,
    __bf16* c_b, __bf16* xb2, __bf16* xb4, __bf16* u_b, __bf16* z_b,
    float* __restrict__ out, int* bar)
{
  __shared__ __bf16 A[16 * STR];
  __shared__ float P[2176];

  const int wg = blockIdx.x;
  const int g = wg >> 3, p = wg & 7;
  const int tid = threadIdx.x;
  const int w = tid >> 6, lane = tid & 63;
  const int rc = lane & 15, row0 = (lane >> 4) * 4;
  const int am0 = g * 16;
  const int col = 64 * p + w * 16 + rc;       // valid for epilogue waves w<4
  int* slots = bar + g * 256;
  int ep = 0;

  f32x4 base_p, c_p, x_p, z_p = {0.f, 0.f, 0.f, 0.f};

  // BASE: base = xy @ Wcab + bc   (K=1024; xy from aux -> normal loads)
  stageA<10, false>(A, xy_b + (size_t)am0 * 1024);
  __syncthreads();
  gemm_ks<16>(A, WcabT, 64 * p, P);
  __syncthreads();
  if (w < 4) {
    f32x4 v = red_ks(P);
#pragma unroll
    for (int e = 0; e < 4; ++e) {
      base_p[e] = v[e] + bc[col];
      cstore_bf16(c_b + (size_t)(am0 + row0 + e) * 512 + col, (__bf16)base_p[e]);
    }
  }
  gbar(slots, p, ++ep);

  for (int r = 0; r < 6; ++r) {
    if (r > 0) {  // S1: c = base + z @ Wcc
      stageA<9, true>(A, z_b + (size_t)am0 * 512);
      __syncthreads();
      gemm_ks<8>(A, WccT, 64 * p, P);
      __syncthreads();
      if (w < 4) {
        f32x4 v = red_ks(P);
#pragma unroll
        for (int e = 0; e < 4; ++e) {
          c_p[e] = base_p[e] + v[e];
          cstore_bf16(c_b + (size_t)(am0 + row0 + e) * 512 + col, (__bf16)c_p[e]);
        }
      }
      gbar(slots, p, ++ep);
    } else {
      c_p = base_p;
    }
#pragma unroll
    for (int l = 0; l < 2; ++l) {
      // S2: x = resid + LN1(A) @ Weff + beff
      stageA<9, true>(A, (l ? xb4 : c_b) + (size_t)am0 * 512);
      __syncthreads();
      ln_lds(A, ln1g + l * 512, ln1b + l * 512);
      __syncthreads();
      gemm_ks<8>(A, WeffT + l * 262144, 64 * p, P);
      __syncthreads();
      if (w < 4) {
        f32x4 v = red_ks(P);
#pragma unroll
        for (int e = 0; e < 4; ++e) {
          float res = l ? x_p[e] : c_p[e];
          x_p[e] = v[e] + beff[l * 512 + col] + res;
          cstore_bf16(xb2 + (size_t)(am0 + row0 + e) * 512 + col, (__bf16)x_p[e]);
        }
      }
      gbar(slots, p, ++ep);
      // S3: u = gelu(LN2(x) @ w1 + b1)  — full-K, 8 waves x 2 tiles
      stageA<9, true>(A, xb2 + (size_t)am0 * 512);
      __syncthreads();
      ln_lds(A, ln2g + l * 512, ln2b + l * 512);
      __syncthreads();
      {
        const __bf16* ap = A + rc * STR + (lane >> 4) * 8;
#pragma unroll
        for (int nt2 = 0; nt2 < 2; ++nt2) {
          const int n0 = 256 * p + w * 32 + nt2 * 16;
          const __bf16* bp = w1T + l * 1048576 + (size_t)(n0 + rc) * 512 + (lane >> 4) * 8;
          f32x4 acc = {0.f, 0.f, 0.f, 0.f};
#pragma unroll
          for (int t = 0; t < 16; ++t)
            acc = __builtin_amdgcn_mfma_f32_16x16x32_bf16(
                *(const bf16x8*)(ap + t * 32), *(const bf16x8*)(bp + t * 32), acc, 0, 0, 0);
          const int col3 = n0 + rc;
#pragma unroll
          for (int e = 0; e < 4; ++e) {
            float v = gelu_f(acc[e] + b1f[l * 2048 + col3]);
            cstore_bf16(u_b + (size_t)(am0 + row0 + e) * 2048 + col3, (__bf16)v);
          }
        }
      }
      gbar(slots, p, ++ep);
      // S4: x = x + u @ w2 + b2 ; l==1 accumulates into z (r==5 -> d_out)
      stageA<11, true>(A, u_b + (size_t)am0 * 2048);
      __syncthreads();
      gemm_ks<32>(A, w2T + l * 1048576, 64 * p, P);
      __syncthreads();
      if (w < 4) {
        f32x4 v = red_ks(P);
        if (l == 0) {
#pragma unroll
          for (int e = 0; e < 4; ++e) {
            x_p[e] = v[e] + b2f[col] + x_p[e];
            cstore_bf16(xb4 + (size_t)(am0 + row0 + e) * 512 + col, (__bf16)x_p[e]);
          }
        } else {
#pragma unroll
          for (int e = 0; e < 4; ++e) {
            z_p[e] += v[e] + b2f[512 + col] + x_p[e];
            if (r < 5) cstore_bf16(z_b + (size_t)(am0 + row0 + e) * 512 + col, (__bf16)z_p[e]);
            else       out[(size_t)(am0 + row0 + e) * 512 + col] = z_p[e];
          }
        }
      }
      if (!(r == 5 && l == 1)) gbar(slots, p, ++ep);
    }
  }
}

extern "C" void kernel_launch(void* const* d_in, const int* in_sizes, int n_in,
                              void* d_out, int out_size, void* d_ws, size_t ws_size,
                              hipStream_t stream) {
  const float* x_encoded = (const float*)d_in[0];
  const float* y_current = (const float*)d_in[1];
  const float* Wpi  = (const float*)d_in[2];
  const float* bpi  = (const float*)d_in[3];
  const float* Wpa  = (const float*)d_in[4];
  const float* bpa  = (const float*)d_in[5];
  const float* Wc   = (const float*)d_in[6];
  const float* bc   = (const float*)d_in[7];
  const float* ln1g = (const float*)d_in[8];
  const float* ln1b = (const float*)d_in[9];
  const float* wqkv = (const float*)d_in[10];
  const float* bqkv = (const float*)d_in[11];
  const float* wo   = (const float*)d_in[12];
  const float* bo   = (const float*)d_in[13];
  const float* ln2g = (const float*)d_in[14];
  const float* ln2b = (const float*)d_in[15];
  const float* w1f  = (const float*)d_in[16];
  const float* b1f  = (const float*)d_in[17];
  const float* w2f  = (const float*)d_in[18];
  const float* b2f  = (const float*)d_in[19];
  (void)in_sizes; (void)n_in; (void)out_size; (void)ws_size;

  char* wsb = (char*)d_ws;
  size_t off = 0;
  auto carve = [&](size_t bytes) -> void* {
    void* p = wsb + off;
    off += (bytes + 255) & ~(size_t)255;
    return p;
  };
  __bf16* xp_b    = (__bf16*)carve(131072 * 2);
  __bf16* y_b     = (__bf16*)carve(32768 * 2);
  __bf16* WpiT    = (__bf16*)carve(524288 * 2);
  __bf16* WpaT    = (__bf16*)carve(131072 * 2);
  __bf16* WcabT   = (__bf16*)carve(524288 * 2);
  __bf16* WccT    = (__bf16*)carve(262144 * 2);
  __bf16* w1T     = (__bf16*)carve(2097152 * 2);
  __bf16* w2T     = (__bf16*)carve(2097152 * 2);
  __bf16* woT     = (__bf16*)carve(524288 * 2);
  __bf16* Wv_b    = (__bf16*)carve(524288 * 2);
  __bf16* WeffT   = (__bf16*)carve(524288 * 2);
  float*  beff    = (float*) carve(1024 * 4);
  __bf16* xy_b    = (__bf16*)carve(131072 * 2);
  __bf16* c_b     = (__bf16*)carve(65536 * 2);
  __bf16* xb2     = (__bf16*)carve(65536 * 2);
  __bf16* xb4     = (__bf16*)carve(65536 * 2);
  __bf16* u_b     = (__bf16*)carve(262144 * 2);
  __bf16* z_b     = (__bf16*)carve(65536 * 2);
  int*    d_bar   = (int*)   carve(16384);

  hipMemsetAsync(d_bar, 0, 16384, stream);
  prep_kernel<<<6804, 256, 0, stream>>>(x_encoded, Wpi, Wpa, Wc, w1f, w2f, wo,
      wqkv, y_current, bqkv, bo, xp_b, WpiT, WpaT, WcabT, WccT, w1T, w2T, woT,
      Wv_b, y_b, beff);
  aux_kernel<<<640, 256, 0, stream>>>(woT, Wv_b, xp_b, y_b, WpiT, WpaT,
      bpi, bpa, WeffT, xy_b);
  mega_kernel<<<64, 512, 0, stream>>>(
      xy_b, WcabT, WccT, WeffT, w1T, w2T, bc, beff,
      ln1g, ln1b, ln2g, ln2b, b1f, b2f,
      c_b, xb2, xb4, u_b, z_b,
      (float*)d_out, d_bar);
}

// Round 11
// 472.097 us; speedup vs baseline: 4.5991x; 1.0603x over previous
//
#include <hip/hip_runtime.h>
#include <math.h>

typedef __bf16 bf16x8 __attribute__((ext_vector_type(8)));
typedef __bf16 bf16x4 __attribute__((ext_vector_type(4)));
typedef float  f32x4  __attribute__((ext_vector_type(4)));
typedef unsigned long long u64;

#define STR 1048   // A-tile LDS stride (bf16): 12*rc bank-start spread (~2-way)
#define UST 280    // u-tile LDS stride

__device__ __forceinline__ float gelu_f(float x) {
  const float k0 = 0.7978845608028654f;
  const float k1 = 0.044715f;
  float x3 = x * x * x;
  return 0.5f * x * (1.0f + tanhf(k0 * (x + k1 * x3)));
}

// coherent (agent-scope, IF$-backed) accessors: bypass non-coherent per-XCD L2
__device__ __forceinline__ u64 cload8(const void* p) {
  return __hip_atomic_load((u64*)p, __ATOMIC_RELAXED, __HIP_MEMORY_SCOPE_AGENT);
}
__device__ __forceinline__ float cloadf(const float* p) {
  unsigned v = __hip_atomic_load((const unsigned*)p, __ATOMIC_RELAXED, __HIP_MEMORY_SCOPE_AGENT);
  return __builtin_bit_cast(float, v);
}
__device__ __forceinline__ void cstore_bf16(__bf16* p, __bf16 h) {
  __hip_atomic_store((short*)p, __builtin_bit_cast(short, h),
                     __ATOMIC_RELAXED, __HIP_MEMORY_SCOPE_AGENT);
}
__device__ __forceinline__ void cstoref(float* p, float v) {
  __hip_atomic_store((unsigned*)p, __builtin_bit_cast(unsigned, v),
                     __ATOMIC_RELAXED, __HIP_MEMORY_SCOPE_AGENT);
}

// ---------------- prep: pool + weight transposes + Wv pack + y conv + beff ----------------
__global__ __launch_bounds__(256) void prep_kernel(
    const float* __restrict__ xe,
    const float* __restrict__ Wpi, const float* __restrict__ Wpa,
    const float* __restrict__ Wc,  const float* __restrict__ w1f,
    const float* __restrict__ w2f, const float* __restrict__ wo,
    const float* __restrict__ wqkv, const float* __restrict__ y,
    const float* __restrict__ bqkv, const float* __restrict__ bo,
    __bf16* __restrict__ xp_b,
    __bf16* __restrict__ WpiT, __bf16* __restrict__ WpaT,
    __bf16* __restrict__ WcabT, __bf16* __restrict__ WccT,
    __bf16* __restrict__ w1T,  __bf16* __restrict__ w2T,
    __bf16* __restrict__ woT,  __bf16* __restrict__ Wv_b,
    __bf16* __restrict__ y_b,  float* __restrict__ beff)
{
  int bid = blockIdx.x;
  int tid = threadIdx.x;
  if (bid < 512) {               // mean pool (128,512,1024) -> (128,1024) bf16
    int b = bid >> 2;
    int c = (bid & 3) * 256 + tid;
    const float* p = xe + (size_t)b * 512 * 1024 + c;
    float s = 0.f;
#pragma unroll 16
    for (int i = 0; i < 512; ++i) s += p[(size_t)i * 1024];
    xp_b[b * 1024 + c] = (__bf16)(s * (1.f / 512.f));
  } else if (bid < 6528) {       // transposes fp32 -> bf16 (N x K layout)
    int t = bid - 512;
    const float* src; __bf16* dst; int R, C;
    if      (t < 512)  {            src = Wpi;            dst = WpiT;          R = 1024; C = 512;  }
    else if (t < 640)  { t -= 512;  src = Wpa;            dst = WpaT;          R = 256;  C = 512;  }
    else if (t < 1152) { t -= 640;  src = Wc;             dst = WcabT;         R = 1024; C = 512;  }
    else if (t < 1408) { t -= 1152; src = Wc + 1024*512;  dst = WccT;          R = 512;  C = 512;  }
    else if (t < 2432) { t -= 1408; src = w1f;            dst = w1T;           R = 512;  C = 2048; }
    else if (t < 3456) { t -= 2432; src = w1f + 512*2048; dst = w1T + 1048576; R = 512;  C = 2048; }
    else if (t < 4480) { t -= 3456; src = w2f;            dst = w2T;           R = 2048; C = 512;  }
    else if (t < 5504) { t -= 4480; src = w2f + 2048*512; dst = w2T + 1048576; R = 2048; C = 512;  }
    else if (t < 5760) { t -= 5504; src = wo;             dst = woT;           R = 512;  C = 512;  }
    else               { t -= 5760; src = wo + 512*512;   dst = woT + 262144;  R = 512;  C = 512;  }
    int nbc = C / 32;
    int r0 = (t / nbc) * 32;
    int c0 = (t % nbc) * 32;
    __shared__ float tt[32][33];
    int tx = tid & 31, ty = tid >> 5;
#pragma unroll
    for (int i = 0; i < 32; i += 8)
      tt[ty + i][tx] = src[(size_t)(r0 + ty + i) * C + c0 + tx];
    __syncthreads();
#pragma unroll
    for (int i = 0; i < 32; i += 8)
      dst[(size_t)(c0 + ty + i) * R + r0 + tx] = (__bf16)tt[tx][ty + i];
  } else if (bid < 6784) {       // Wv pack
    int e0 = ((bid - 6528) * 256 + tid) * 8;
    int l = e0 >> 18, rem = e0 & 262143;
    int m = rem >> 9, k = rem & 511;
    const float* s = wqkv + (size_t)l * 786432 + (size_t)m * 1536 + 1024 + k;
#pragma unroll
    for (int j = 0; j < 8; ++j) Wv_b[e0 + j] = (__bf16)s[j];
  } else if (bid < 6800) {       // y -> bf16
    int e0 = ((bid - 6784) * 256 + tid) * 8;
#pragma unroll
    for (int j = 0; j < 8; ++j) y_b[e0 + j] = (__bf16)y[e0 + j];
  } else {                       // beff[l] = bv @ wo + bo
    int b2 = bid - 6800;
    int l = b2 >> 1;
    int n = (b2 & 1) * 256 + tid;
    const float* bv = bqkv + l * 1536 + 1024;
    const float* w  = wo + (size_t)l * 262144;
    float s = bo[l * 512 + n];
#pragma unroll 8
    for (int k = 0; k < 512; ++k) s += bv[k] * w[(size_t)k * 512 + n];
    beff[l * 512 + n] = s;
  }
}

// ---------------- LDS-tile GEMM (aux only) ----------------
template<int NT, bool BIAS>
__device__ __forceinline__ void gemm32(
    const __bf16* A, const __bf16* Bt, int bm0, int bn0,
    const float* bias, __bf16* outb, int ldo,
    __bf16* AL, __bf16* BL)
{
  const int tid = threadIdx.x;
  constexpr int K = NT * 64;
  const int row = tid >> 3;
  const int kcol = (tid & 7) * 8;

  const __bf16* Ab0 = A + (size_t)(bm0 + row) * K + kcol;
  const __bf16* Bb0 = Bt + (size_t)(bn0 + row) * K + kcol;

  u64 ra0[4], ra1[4], rb0[4], rb1[4];
  auto issue = [&](int t, int s) {
    const __bf16* ap = Ab0 + t * 64;
    const __bf16* bp = Bb0 + t * 64;
    ra0[s] = *(const u64*)ap; ra1[s] = *(const u64*)(ap + 4);
    rb0[s] = *(const u64*)bp; rb1[s] = *(const u64*)(bp + 4);
  };
#pragma unroll
  for (int s = 0; s < 4; ++s) issue(s, s);

  f32x4 acc = {0.f, 0.f, 0.f, 0.f};
  const int wave = tid >> 6, lane = tid & 63;
  const int wr = (wave >> 1) * 16, wc = (wave & 1) * 16;
  const int lr = lane & 15, lk8 = (lane >> 4) * 8;

  for (int ttc = 0; ttc < NT / 4; ++ttc) {
#pragma unroll
    for (int ti = 0; ti < 4; ++ti) {
      const int t = ttc * 4 + ti;
      __bf16* al = AL + (ti & 1) * 2304 + row * 72 + kcol;
      __bf16* bl = BL + (ti & 1) * 2304 + row * 72 + kcol;
      *(u64*)al = ra0[ti]; *(u64*)(al + 4) = ra1[ti];
      *(u64*)bl = rb0[ti]; *(u64*)(bl + 4) = rb1[ti];
      __syncthreads();
      if (t + 4 < NT) issue(t + 4, ti);
      const __bf16* Ar = AL + (ti & 1) * 2304 + (wr + lr) * 72;
      const __bf16* Br = BL + (ti & 1) * 2304 + (wc + lr) * 72;
      bf16x8 a0 = *(const bf16x8*)(Ar + lk8);
      bf16x8 b0v = *(const bf16x8*)(Br + lk8);
      acc = __builtin_amdgcn_mfma_f32_16x16x32_bf16(a0, b0v, acc, 0, 0, 0);
      bf16x8 a1 = *(const bf16x8*)(Ar + 32 + lk8);
      bf16x8 b1v = *(const bf16x8*)(Br + 32 + lk8);
      acc = __builtin_amdgcn_mfma_f32_16x16x32_bf16(a1, b1v, acc, 0, 0, 0);
      __syncthreads();
    }
  }

  const int er = bm0 + wr + (lane >> 4) * 4;
  const int ec = bn0 + wc + lr;
#pragma unroll
  for (int e = 0; e < 4; ++e) {
    float v = acc[e];
    if (BIAS) v += bias[ec];
    outb[(size_t)(er + e) * ldo + ec] = (__bf16)v;
  }
}

// ---------------- aux: Weff GEMMs + projections ----------------
__global__ __launch_bounds__(256) void aux_kernel(
    const __bf16* __restrict__ woT, const __bf16* __restrict__ Wv_b,
    const __bf16* __restrict__ xp_b, const __bf16* __restrict__ y_b,
    const __bf16* __restrict__ WpiT, const __bf16* __restrict__ WpaT,
    const float* __restrict__ bpi, const float* __restrict__ bpa,
    __bf16* __restrict__ WeffT, __bf16* __restrict__ xy_b)
{
  __shared__ __bf16 AL[2 * 32 * 72];
  __shared__ __bf16 BL[2 * 32 * 72];
  int bid = blockIdx.x;
  if (bid < 512) {        // WeffT[l][n][j] = sum_m woT[l][n][m] * Wv_b[l][j][m]
    int l = bid >> 8, t = bid & 255;
    gemm32<8, false>(woT + l * 262144, Wv_b + l * 262144,
        (t >> 4) * 32, (t & 15) * 32, nullptr, WeffT + l * 262144, 512, AL, BL);
  } else if (bid < 576) { // xy[:, :512] = xp @ Wpi + bpi
    int t = bid - 512;
    gemm32<16, true>(xp_b, WpiT, (t >> 4) * 32, (t & 15) * 32,
        bpi, xy_b, 1024, AL, BL);
  } else {                // xy[:, 512:] = y @ Wpa + bpa
    int t = bid - 576;
    gemm32<4, true>(y_b, WpaT, (t >> 4) * 32, (t & 15) * 32,
        bpa, xy_b + 512, 1024, AL, BL);
  }
}

// ---------------- 8-WG group barrier: own slot store + all-to-all poll ----------------
__device__ __forceinline__ void gbar(int* slots, int p, int ep) {
  asm volatile("s_waitcnt vmcnt(0)" ::: "memory");
  __syncthreads();
  if (threadIdx.x == 0)
    __hip_atomic_store(slots + p * 32, ep, __ATOMIC_RELAXED, __HIP_MEMORY_SCOPE_AGENT);
  if (threadIdx.x < 8) {
    while (__hip_atomic_load(slots + threadIdx.x * 32, __ATOMIC_RELAXED,
                             __HIP_MEMORY_SCOPE_AGENT) < ep)
      __builtin_amdgcn_s_sleep(1);
  }
  __syncthreads();
}

// ---------------- stage 16 x K rows into LDS (flat copy, 512 threads) ----------
template<int LGK, bool COH>
__device__ __forceinline__ void stage_plain(__bf16* A, const __bf16* __restrict__ src) {
  constexpr int K = 1 << LGK;
#pragma unroll
  for (int i = threadIdx.x; i < (16 << LGK) / 4; i += 512) {
    const int i4 = i * 4;
    u64 q;
    if (COH) q = cload8(src + i4);
    else     q = *(const u64*)(src + i4);
    *(u64*)&A[(i4 >> LGK) * STR + (i4 & (K - 1))] = q;
  }
}

// ---------------- stage 16x512 + fused LayerNorm (stats in registers during load) ----------
__device__ __forceinline__ void stage_ln(__bf16* A, const __bf16* __restrict__ src,
                                         const float* __restrict__ g,
                                         const float* __restrict__ bb) {
  const int t = threadIdx.x;
  const int row = t >> 5;
  const int c0 = (t & 31) * 16;
  const __bf16* sp = src + row * 512 + c0;
  bf16x4 v[4];
  v[0] = __builtin_bit_cast(bf16x4, cload8(sp));
  v[1] = __builtin_bit_cast(bf16x4, cload8(sp + 4));
  v[2] = __builtin_bit_cast(bf16x4, cload8(sp + 8));
  v[3] = __builtin_bit_cast(bf16x4, cload8(sp + 12));
  float s = 0.f, s2 = 0.f;
#pragma unroll
  for (int q = 0; q < 4; ++q)
#pragma unroll
    for (int j = 0; j < 4; ++j) { float f = (float)v[q][j]; s += f; s2 += f * f; }
#pragma unroll
  for (int m = 1; m <= 16; m <<= 1) { s += __shfl_xor(s, m); s2 += __shfl_xor(s2, m); }
  const float mu = s * (1.f / 512.f);
  const float rs = rsqrtf(s2 * (1.f / 512.f) - mu * mu + 1e-5f);
#pragma unroll
  for (int q = 0; q < 4; ++q) {
    const f32x4 gq = *(const f32x4*)(g + c0 + q * 4);
    const f32x4 bq = *(const f32x4*)(bb + c0 + q * 4);
#pragma unroll
    for (int j = 0; j < 4; ++j)
      v[q][j] = (__bf16)(((float)v[q][j] - mu) * rs * gq[j] + bq[j]);
    *(u64*)&A[row * STR + c0 + q * 4] = __builtin_bit_cast(u64, v[q]);
  }
}

// ---------------- K-split GEMM: 8 waves = 4 tiles x 2 K-halves; partials to P ----------------
template<int KT>
__device__ __forceinline__ void gemm_ks(const __bf16* A, const __bf16* __restrict__ Bt,
                                        int ncol0, float* P) {
  const int tid = threadIdx.x;
  const int w = tid >> 6, lane = tid & 63;
  const int rc = lane & 15, k8 = (lane >> 4) * 8;
  const int nt = w & 3, kh = w >> 2;
  const __bf16* ap = A + rc * STR + kh * (KT * 32) + k8;
  const __bf16* bp = Bt + (size_t)(ncol0 + nt * 16 + rc) * (KT * 64) + kh * (KT * 32) + k8;
  f32x4 acc = {0.f, 0.f, 0.f, 0.f};
#pragma unroll
  for (int t = 0; t < KT; ++t)
    acc = __builtin_amdgcn_mfma_f32_16x16x32_bf16(
        *(const bf16x8*)(ap + t * 32), *(const bf16x8*)(bp + t * 32), acc, 0, 0, 0);
  const int row0 = (lane >> 4) * 4;
#pragma unroll
  for (int e = 0; e < 4; ++e)
    P[kh * 1088 + (row0 + e) * 68 + nt * 16 + rc] = acc[e];
}

__device__ __forceinline__ f32x4 red_ks(const float* P) {
  const int tid = threadIdx.x;
  const int w = tid >> 6, lane = tid & 63;
  const int rc = lane & 15, row0 = (lane >> 4) * 4;
  f32x4 v;
#pragma unroll
  for (int e = 0; e < 4; ++e)
    v[e] = P[(row0 + e) * 68 + w * 16 + rc] + P[1088 + (row0 + e) * 68 + w * 16 + rc];
  return v;
}

// ---------------- mega: 64 WGs = 8 row-groups x 8 col-slices; S3+S4 fused ----------------
__global__ __launch_bounds__(512, 1) void mega_kernel(
    const __bf16* __restrict__ xy_b, const __bf16* __restrict__ WcabT,
    const __bf16* __restrict__ WccT, const __bf16* __restrict__ WeffT,
    const __bf16* __restrict__ w1T, const __bf16* __restrict__ w2T,
    const float* __restrict__ bc, const float* __restrict__ beff,
    const float* __restrict__ ln1g, const float* __restrict__ ln1b,
    const float* __restrict__ ln2g, const float* __restrict__ ln2b,
    const float* __restrict__ b1f, const float* __restrict__ b2f,
    __bf16* c_b, __bf16* xb2, __bf16* xb4, __bf16* z_b, float* P4ws,
    float* __restrict__ out, int* bar)
{
  __shared__ __bf16 A[16 * STR];
  __shared__ __bf16 UB[16 * UST];
  __shared__ float P[2176];

  const int wg = blockIdx.x;
  const int g = wg >> 3, p = wg & 7;
  const int tid = threadIdx.x;
  const int w = tid >> 6, lane = tid & 63;
  const int rc = lane & 15, k8 = (lane >> 4) * 8, row0 = (lane >> 4) * 4;
  const int am0 = g * 16;
  const int col = 64 * p + w * 16 + rc;          // epilogue cols (waves w<4)
  int* slots = bar + g * 256;
  int ep = 0;

  f32x4 base_p, c_p, x_p, z_p = {0.f, 0.f, 0.f, 0.f};

  // BASE: base = xy @ Wcab + bc   (K=1024; xy from aux -> normal loads)
  stage_plain<10, false>(A, xy_b + (size_t)am0 * 1024);
  __syncthreads();
  gemm_ks<16>(A, WcabT, 64 * p, P);
  __syncthreads();
  if (w < 4) {
    f32x4 v = red_ks(P);
#pragma unroll
    for (int e = 0; e < 4; ++e) {
      base_p[e] = v[e] + bc[col];
      cstore_bf16(c_b + (size_t)(am0 + row0 + e) * 512 + col, (__bf16)base_p[e]);
    }
  }
  gbar(slots, p, ++ep);

  for (int r = 0; r < 6; ++r) {
    if (r > 0) {  // S1: c = base + z @ Wcc
      stage_plain<9, true>(A, z_b + (size_t)am0 * 512);
      __syncthreads();
      gemm_ks<8>(A, WccT, 64 * p, P);
      __syncthreads();
      if (w < 4) {
        f32x4 v = red_ks(P);
#pragma unroll
        for (int e = 0; e < 4; ++e) {
          c_p[e] = base_p[e] + v[e];
          cstore_bf16(c_b + (size_t)(am0 + row0 + e) * 512 + col, (__bf16)c_p[e]);
        }
      }
      gbar(slots, p, ++ep);
    } else {
      c_p = base_p;
    }
#pragma unroll
    for (int l = 0; l < 2; ++l) {
      const int lo = l * 512;
      // S2: x = resid + LN1(A) @ Weff + beff   (LN fused into stage)
      stage_ln(A, (l ? xb4 : c_b) + (size_t)am0 * 512, ln1g + lo, ln1b + lo);
      __syncthreads();
      gemm_ks<8>(A, WeffT + l * 262144, 64 * p, P);
      __syncthreads();
      if (w < 4) {
        f32x4 v = red_ks(P);
#pragma unroll
        for (int e = 0; e < 4; ++e) {
          float res = l ? x_p[e] : c_p[e];
          x_p[e] = v[e] + beff[lo + col] + res;
          cstore_bf16(xb2 + (size_t)(am0 + row0 + e) * 512 + col, (__bf16)x_p[e]);
        }
      }
      gbar(slots, p, ++ep);
      // T3 (S3+S4 fused): stage LN2(x); u(own 256 cols)->LDS; partials = u @ w2-rowslice
      stage_ln(A, xb2 + (size_t)am0 * 512, ln2g + lo, ln2b + lo);
      __syncthreads();
      {
        // GEMM1: u = gelu(LN2(x) @ w1[:, own 256 cols] + b1), into LDS
        const __bf16* ap = A + rc * STR + k8;
#pragma unroll
        for (int nt2 = 0; nt2 < 2; ++nt2) {
          const int lcr = w * 32 + nt2 * 16 + rc;     // local u col 0..255
          const __bf16* bp = w1T + l * 1048576 + (size_t)(256 * p + lcr) * 512 + k8;
          f32x4 acc = {0.f, 0.f, 0.f, 0.f};
#pragma unroll
          for (int t = 0; t < 16; ++t)
            acc = __builtin_amdgcn_mfma_f32_16x16x32_bf16(
                *(const bf16x8*)(ap + t * 32), *(const bf16x8*)(bp + t * 32), acc, 0, 0, 0);
#pragma unroll
          for (int e = 0; e < 4; ++e)
            UB[(row0 + e) * UST + lcr] =
                (__bf16)gelu_f(acc[e] + b1f[l * 2048 + 256 * p + lcr]);
        }
      }
      __syncthreads();
      {
        // GEMM2: partials(16x512) = u_sl(16x256) @ w2[256p rows, all 512 cols]
        const __bf16* up = UB + rc * UST + k8;
#pragma unroll
        for (int nt = 0; nt < 4; ++nt) {
          const int n0r = w * 64 + nt * 16 + rc;
          const __bf16* bp = w2T + l * 1048576 + (size_t)n0r * 2048 + 256 * p + k8;
          f32x4 acc = {0.f, 0.f, 0.f, 0.f};
#pragma unroll
          for (int t = 0; t < 8; ++t)
            acc = __builtin_amdgcn_mfma_f32_16x16x32_bf16(
                *(const bf16x8*)(up + t * 32), *(const bf16x8*)(bp + t * 32), acc, 0, 0, 0);
          float* pw = P4ws + ((size_t)(g * 8 + p) * 16 + row0) * 512 + n0r;
#pragma unroll
          for (int e = 0; e < 4; ++e) cstoref(pw + e * 512, acc[e]);
        }
      }
      gbar(slots, p, ++ep);
      // T4: reduce 8 partial strips for own cols; residual in regs
      if (w < 4) {
        f32x4 sum = {0.f, 0.f, 0.f, 0.f};
#pragma unroll
        for (int e = 0; e < 4; ++e) {
          const float* pr = P4ws + ((size_t)(g * 8) * 16 + row0 + e) * 512 + col;
#pragma unroll
          for (int pp = 0; pp < 8; ++pp)
            sum[e] += cloadf(pr + (size_t)pp * 16 * 512);
        }
        if (l == 0) {
#pragma unroll
          for (int e = 0; e < 4; ++e) {
            x_p[e] = sum[e] + b2f[col] + x_p[e];
            cstore_bf16(xb4 + (size_t)(am0 + row0 + e) * 512 + col, (__bf16)x_p[e]);
          }
        } else {
#pragma unroll
          for (int e = 0; e < 4; ++e) {
            z_p[e] += sum[e] + b2f[512 + col] + x_p[e];
            if (r < 5) cstore_bf16(z_b + (size_t)(am0 + row0 + e) * 512 + col, (__bf16)z_p[e]);
            else       out[(size_t)(am0 + row0 + e) * 512 + col] = z_p[e];
          }
        }
      }
      if (!(r == 5 && l == 1)) gbar(slots, p, ++ep);
    }
  }
}

extern "C" void kernel_launch(void* const* d_in, const int* in_sizes, int n_in,
                              void* d_out, int out_size, void* d_ws, size_t ws_size,
                              hipStream_t stream) {
  const float* x_encoded = (const float*)d_in[0];
  const float* y_current = (const float*)d_in[1];
  const float* Wpi  = (const float*)d_in[2];
  const float* bpi  = (const float*)d_in[3];
  const float* Wpa  = (const float*)d_in[4];
  const float* bpa  = (const float*)d_in[5];
  const float* Wc   = (const float*)d_in[6];
  const float* bc   = (const float*)d_in[7];
  const float* ln1g = (const float*)d_in[8];
  const float* ln1b = (const float*)d_in[9];
  const float* wqkv = (const float*)d_in[10];
  const float* bqkv = (const float*)d_in[11];
  const float* wo   = (const float*)d_in[12];
  const float* bo   = (const float*)d_in[13];
  const float* ln2g = (const float*)d_in[14];
  const float* ln2b = (const float*)d_in[15];
  const float* w1f  = (const float*)d_in[16];
  const float* b1f  = (const float*)d_in[17];
  const float* w2f  = (const float*)d_in[18];
  const float* b2f  = (const float*)d_in[19];
  (void)in_sizes; (void)n_in; (void)out_size; (void)ws_size;

  char* wsb = (char*)d_ws;
  size_t off = 0;
  auto carve = [&](size_t bytes) -> void* {
    void* p = wsb + off;
    off += (bytes + 255) & ~(size_t)255;
    return p;
  };
  __bf16* xp_b    = (__bf16*)carve(131072 * 2);
  __bf16* y_b     = (__bf16*)carve(32768 * 2);
  __bf16* WpiT    = (__bf16*)carve(524288 * 2);
  __bf16* WpaT    = (__bf16*)carve(131072 * 2);
  __bf16* WcabT   = (__bf16*)carve(524288 * 2);
  __bf16* WccT    = (__bf16*)carve(262144 * 2);
  __bf16* w1T     = (__bf16*)carve(2097152 * 2);
  __bf16* w2T     = (__bf16*)carve(2097152 * 2);
  __bf16* woT     = (__bf16*)carve(524288 * 2);
  __bf16* Wv_b    = (__bf16*)carve(524288 * 2);
  __bf16* WeffT   = (__bf16*)carve(524288 * 2);
  float*  beff    = (float*) carve(1024 * 4);
  __bf16* xy_b    = (__bf16*)carve(131072 * 2);
  __bf16* c_b     = (__bf16*)carve(65536 * 2);
  __bf16* xb2     = (__bf16*)carve(65536 * 2);
  __bf16* xb4     = (__bf16*)carve(65536 * 2);
  __bf16* z_b     = (__bf16*)carve(65536 * 2);
  float*  P4ws    = (float*) carve(524288 * 4);   // [8 groups][8 producers][16][512] f32
  int*    d_bar   = (int*)   carve(16384);

  hipMemsetAsync(d_bar, 0, 16384, stream);
  prep_kernel<<<6804, 256, 0, stream>>>(x_encoded, Wpi, Wpa, Wc, w1f, w2f, wo,
      wqkv, y_current, bqkv, bo, xp_b, WpiT, WpaT, WcabT, WccT, w1T, w2T, woT,
      Wv_b, y_b, beff);
  aux_kernel<<<640, 256, 0, stream>>>(woT, Wv_b, xp_b, y_b, WpiT, WpaT,
      bpi, bpa, WeffT, xy_b);
  mega_kernel<<<64, 512, 0, stream>>>(
      xy_b, WcabT, WccT, WeffT, w1T, w2T, bc, beff,
      ln1g, ln1b, ln2g, ln2b, b1f, b2f,
      c_b, xb2, xb4, z_b, P4ws,
      (float*)d_out, d_bar);
}